// Round 15
// baseline (301.653 us; speedup 1.0000x reference)
//
#include <hip/hip_runtime.h>
#include <cstdint>
#include <cstddef>

typedef float f32x4 __attribute__((ext_vector_type(4)));
typedef _Float16 f16x8 __attribute__((ext_vector_type(8)));
typedef _Float16 f16x4 __attribute__((ext_vector_type(4)));
typedef short s16x8 __attribute__((ext_vector_type(8)));

__device__ __forceinline__ float elu_f(float x) { return x > 0.f ? x : expm1f(x); }

__device__ __forceinline__ unsigned short f2bf(float f) {
    unsigned u = __float_as_uint(f);
    return (unsigned short)((u + 0x7FFFu + ((u >> 16) & 1u)) >> 16);
}
__device__ __forceinline__ float bf2f(unsigned short b) {
    return __uint_as_float(((unsigned)b) << 16);
}

__device__ __forceinline__ void gload_lds16(const void* g, void* l)
{
    __builtin_amdgcn_global_load_lds(
        (const __attribute__((address_space(1))) void*)g,
        (__attribute__((address_space(3))) void*)l,
        16, 0, 0);
}

// ================= fused prologue: edge-MLP (+dst count) and the 3 w2 packs =========
// pack layout (proven r5/r6/r8): fp16 chunks [kh*KFTOT+c][COUT][32] with 16B-block swizzle
// blk = (kk>>3) ^ ((n>>1)&3) so linear global_load_lds + swizzled ds_read is conflict-free.
template <int CIN, int COUT, int KFTOT>
__device__ __forceinline__
void pack_body(int bid, int tid, const float* __restrict__ w2, const float* __restrict__ b2,
               _Float16* __restrict__ w2h, int KH, float* tile /* [32][COUT+2] */)
{
    const int kh = bid / KFTOT;
    const int c  = bid - kh * KFTOT;
    const int CP = 32 * COUT;
    for (int i = tid; i < CP; i += 256) {
        int kk = i / COUT, n = i - kk * COUT;
        int kg = c * 32 + kk;
        float v = 0.f;
        if (kg < CIN) v = (kh < KH) ? w2[((size_t)kh * CIN + kg) * COUT + n]
                                    : b2[(size_t)kg * COUT + n];
        tile[kk * (COUT + 2) + n] = v;
    }
    __syncthreads();
    _Float16* outp = w2h + (size_t)bid * CP;
    for (int i = tid; i < CP; i += 256) {
        int n = i >> 5, kk = i & 31;
        int blk = (kk >> 3) ^ ((n >> 1) & 3);
        outp[n * 32 + blk * 8 + (kk & 7)] = (_Float16)tile[kk * (COUT + 2) + n];
    }
}

__global__ __launch_bounds__(256)
void uber_prologue_kernel(const float* __restrict__ ea,
                          const int* __restrict__ dst, int* __restrict__ cnt,
                          const float* __restrict__ w1a, const float* __restrict__ b1a, _Float16* __restrict__ h1T,
                          const float* __restrict__ w1b, const float* __restrict__ b1b, _Float16* __restrict__ h2T,
                          const float* __restrict__ w1c, const float* __restrict__ b1c, _Float16* __restrict__ h3T,
                          int E,
                          const float* __restrict__ w2a, const float* __restrict__ b2a, _Float16* __restrict__ w2h1,
                          const float* __restrict__ w2b, const float* __restrict__ b2b, _Float16* __restrict__ w2h2,
                          const float* __restrict__ w2c, const float* __restrict__ b2c, _Float16* __restrict__ w2h3)
{
    __shared__ __align__(16) float smem[32 * 258];
    const int tid = threadIdx.x;
    const int nEB = E >> 6;
    int b = blockIdx.x;

    if (b < nEB) {
        // ---- edge MLP ----
        const int e0 = b * 64;
        const int el = tid & 63;
        const int cg = tid >> 6;
        if (tid < 64) atomicAdd(&cnt[dst[e0 + tid]], 1);
        float* a = smem;                       // [64][5]
        for (int i = tid; i < 320; i += 256) a[(i / 5) * 5 + (i % 5)] = ea[e0 * 5 + i];
        __syncthreads();
        float av[5];
        #pragma unroll
        for (int j = 0; j < 5; ++j) av[j] = a[el * 5 + j];
        #pragma unroll 4
        for (int t = 0; t < 128; ++t) {
            const int ch = t * 4 + cg;
            float s = b1a[ch];
            #pragma unroll
            for (int j = 0; j < 5; ++j) s = fmaf(av[j], w1a[j * 512 + ch], s);
            h1T[(size_t)ch * E + e0 + el] = (_Float16)fmaxf(s, 0.f);
        }
        #pragma unroll 4
        for (int t = 0; t < 32; ++t) {
            const int ch = t * 4 + cg;
            float s = b1b[ch];
            float u = b1c[ch];
            #pragma unroll
            for (int j = 0; j < 5; ++j) {
                s = fmaf(av[j], w1b[j * 128 + ch], s);
                u = fmaf(av[j], w1c[j * 128 + ch], u);
            }
            h2T[(size_t)ch * E + e0 + el] = (_Float16)fmaxf(s, 0.f);
            h3T[(size_t)ch * E + e0 + el] = (_Float16)fmaxf(u, 0.f);
        }
        return;
    }
    b -= nEB;
    if (b < 513 * 2) { pack_body<37, 128, 2>(b, tid, w2a, b2a, w2h1, 512, smem); return; }
    b -= 513 * 2;
    if (b < 129 * 4) { pack_body<128, 256, 4>(b, tid, w2b, b2b, w2h2, 128, smem); return; }
    b -= 129 * 4;
    pack_body<256, 256, 8>(b, tid, w2c, b2c, w2h3, 128, smem);
}

// ---------------- CSR scan (+ fused graph offsets) ----------------
__global__ __launch_bounds__(256)
void csr_scan_graph_kernel(const int* __restrict__ cnt, int* __restrict__ offs, int N,
                           const int* __restrict__ batch, int* __restrict__ goffs, int B,
                           int NN)
{
    __shared__ int sums[256];
    __shared__ int pref[257];
    const int tid = threadIdx.x;
    const int per = N / 256;
    int loc = 0;
    for (int i = 0; i < per; ++i) loc += cnt[tid * per + i];
    sums[tid] = loc;
    __syncthreads();
    if (tid == 0) {
        int s = 0; pref[0] = 0;
        for (int i = 0; i < 256; ++i) { s += sums[i]; pref[i + 1] = s; }
    }
    __syncthreads();
    int run = pref[tid];
    for (int i = 0; i < per; ++i) { offs[tid * per + i] = run; run += cnt[tid * per + i]; }
    if (tid == 255) offs[N] = run;
    for (int g = tid; g <= B; g += 256) {
        int lo = 0, hi = NN;
        while (lo < hi) { int mid = (lo + hi) >> 1; if (batch[mid] < g) lo = mid + 1; else hi = mid; }
        goffs[g] = lo;
    }
}

__global__ __launch_bounds__(256)
void csr_fill_kernel(const int* __restrict__ dst, const int* __restrict__ offs,
                     int* __restrict__ cur, int* __restrict__ eid, int E)
{
    int e = blockIdx.x * 256 + threadIdx.x;
    if (e < E) {
        int d = dst[e];
        int p = offs[d] + atomicAdd(&cur[d], 1);
        eid[p] = e;
    }
}

// ---------------- MFMA message kernel: r12 structure + h staged in LDS -------------
// part[zz][e][n0+n] = sum_{kh in z range} h[e,kh] * (X[:,cin-range] @ W2[kh][cin-range,:])[e,n]
// BM=512, mf=8, KF=1. h for the block's ENTIRE kh-range staged into LDS once (rows with
// kh>=KH pre-filled with fp16 1.0) -> per-iteration VMEM is ONLY the B-slab DMA; h comes
// from 8 conflict-free ds_read_u16 (120-cyc LDS latency vs 200-900 global).
template <int KH, int CIN, int COUT, int KFTOT, int CSPLIT, int NY, int KHGM>
__global__ __launch_bounds__(256, 2)
void msg_mfma_kernel(const float* __restrict__ xin,      // [*, CIN] fp32 (gathered via src)
                     const _Float16* __restrict__ hT,    // [KH, E] f16
                     const _Float16* __restrict__ w2h,   // packed+swizzled
                     const int* __restrict__ src,
                     _Float16* __restrict__ part,        // [NZ][E][COUT]
                     int E, int khg_per)
{
    constexpr int BM = 512;
    constexpr int KF = KFTOT / CSPLIT;
    static_assert(KF == 1, "mf=8 msg kernel expects one 32-k chunk per block");

    __shared__ __align__(16) _Float16 bsh[2][64][32];
    __shared__ _Float16 s_h[KHGM][512];
    __shared__ int s_src[BM];

    const int tid  = threadIdx.x;
    const int lane = tid & 63;
    const int w    = tid >> 6;        // wave -> rows w*128 .. w*128+127
    const int l15  = lane & 15;
    const int lg   = lane >> 4;       // 0..3  (k-quarter)
    const int swb  = (l15 >> 1) & 3;  // read-side swizzle

    const int nwg = gridDim.x;
    const int bid = blockIdx.x;
    const int swz = (bid & 7) * (nwg >> 3) + (bid >> 3);
    const int m    = swz & 7;          // 8 m-blocks of 512 edges
    const int rest = swz >> 3;
    const int y    = rest % NY;
    const int zz   = rest / NY;
    const int cinH = zz % CSPLIT;
    const int zkh  = zz / CSPLIT;

    const int e0  = m * BM;
    const int n0  = y * 64;
    const int k0  = cinH * 32;
    const int kh0 = zkh * khg_per;
    const int kh1 = min(kh0 + khg_per, KH + 1);
    const int nkh = kh1 - kh0;

    s_src[tid]       = src[e0 + tid];
    s_src[tid + 256] = src[e0 + tid + 256];

    // ---- stage h range into LDS once (coalesced; kh>=KH rows = fp16 1.0) ----
    for (int kk = 0; kk < nkh; ++kk) {
        const int kh = kh0 + kk;
        unsigned v = 0x3C003C00u;      // two fp16 1.0
        if (kh < KH) v = *(const unsigned*)(hT + (size_t)kh * E + e0 + tid * 2);
        *(unsigned*)&s_h[kk][tid * 2] = v;
    }
    __syncthreads();

    // gather A (X rows, this block's 32-k range) into fp16 register fragments
    f16x8 a_[8];
    #pragma unroll
    for (int mf = 0; mf < 8; ++mf) {
        const int eloc = w * 128 + mf * 16 + l15;
        const float* xrow = xin + (size_t)s_src[eloc] * CIN + k0;
        if (CIN % 32 == 0) {
            float4 p0 = *(const float4*)(xrow + lg * 8);
            float4 p1 = *(const float4*)(xrow + lg * 8 + 4);
            a_[mf][0] = (_Float16)p0.x; a_[mf][1] = (_Float16)p0.y;
            a_[mf][2] = (_Float16)p0.z; a_[mf][3] = (_Float16)p0.w;
            a_[mf][4] = (_Float16)p1.x; a_[mf][5] = (_Float16)p1.y;
            a_[mf][6] = (_Float16)p1.z; a_[mf][7] = (_Float16)p1.w;
        } else {
            #pragma unroll
            for (int j = 0; j < 8; ++j) {
                int kk = lg * 8 + j;
                float v = (k0 + kk < CIN) ? xrow[kk] : 0.f;
                a_[mf][j] = (_Float16)v;
            }
        }
    }

    f32x4 msg[8][4];
    #pragma unroll
    for (int mf = 0; mf < 8; ++mf)
        #pragma unroll
        for (int nf = 0; nf < 4; ++nf) msg[mf][nf] = 0.f;

    auto stage = [&](int khg, int pp) {
        if (khg >= kh1) return;
        const size_t chunk = (size_t)khg * KFTOT + cinH;
        const char* g = (const char*)(w2h + (chunk * COUT + n0) * 32) + (size_t)tid * 16;
        char* l = (char*)(&bsh[pp][0][0]) + (tid >> 6) * 1024;
        gload_lds16(g, l);
    };

    stage(kh0, 0);

    int p = 0;
    for (int khg = kh0; khg < kh1; ++khg) {
        __syncthreads();                    // slab p ready (vmcnt drained); p^1 free

        stage(khg + 1, p ^ 1);              // DMA in flight across compute + next barrier

        // h for this kh slab: 8 conflict-free ds_read_u16 from the pre-staged range
        const int klocal = khg - kh0;
        _Float16 hh[8];
        #pragma unroll
        for (int mf = 0; mf < 8; ++mf)
            hh[mf] = s_h[klocal][w * 128 + mf * 16 + l15];

        f16x8 Bv[4];
        #pragma unroll
        for (int nf = 0; nf < 4; ++nf)
            Bv[nf] = *(const f16x8*)&bsh[p][nf * 16 + l15][(lg ^ swb) * 8];

        #pragma unroll
        for (int mf = 0; mf < 8; ++mf) {
            f16x8 ah = a_[mf] * hh[mf];
            #pragma unroll
            for (int nf = 0; nf < 4; ++nf)
                msg[mf][nf] = __builtin_amdgcn_mfma_f32_16x16x32_f16(ah, Bv[nf], msg[mf][nf], 0, 0, 0);
        }
        p ^= 1;
    }

    _Float16* pb = part + ((size_t)zz * E + e0) * COUT + n0;
    #pragma unroll
    for (int mf = 0; mf < 8; ++mf)
        #pragma unroll
        for (int r = 0; r < 4; ++r) {
            const int row = w * 128 + mf * 16 + lg * 4 + r;
            #pragma unroll
            for (int nf = 0; nf < 4; ++nf)
                pb[(size_t)row * COUT + nf * 16 + l15] = (_Float16)msg[mf][nf][r];
        }
}

// ---------------- node GEMM via bf16 hi/lo MFMA + fused CSR gather (r14-proven) -------
// out[n] = elu( x[n]@root + sum_{e: dst=n} sum_z part[z][e] + bias )
template <int CIN, int COUT, int Z>
__global__ __launch_bounds__(256, 2)
void node_mfma_kernel(const float* __restrict__ xin,
                      const float* __restrict__ root,
                      const _Float16* __restrict__ part,
                      const int* __restrict__ offs,
                      const int* __restrict__ eid,
                      const float* __restrict__ bias,
                      float* __restrict__ out, int E)
{
    constexpr int KC    = (CIN + 31) / 32;
    constexpr int NSTEP = KC / 2;

    __shared__ __align__(16) char smem[32768];
    short (*ash)[2][64][32] = (short (*)[2][64][32])smem;
    short (*bsh)[2][64][32] = (short (*)[2][64][32])(smem + 16384);
    float (*csh)[68]        = (float (*)[68])smem;

    const int tid  = threadIdx.x;
    const int lane = tid & 63;
    const int w    = tid >> 6;
    const int l15  = lane & 15;
    const int lg   = lane >> 4;
    const int swb  = (l15 >> 1) & 3;
    const int e0   = blockIdx.x * 64;
    const int n0   = blockIdx.y * 64;

    f32x4 ahh[4], alh[4], ahl[4];
    #pragma unroll
    for (int nf = 0; nf < 4; ++nf) { ahh[nf] = 0.f; alh[nf] = 0.f; ahl[nf] = 0.f; }

    const int srow = tid & 63;
    const int sco  = (tid >> 6) * 16;

    for (int s = 0; s < NSTEP; ++s) {
        __syncthreads();

        {
            const int kbase = s * 64 + sco;
            float v[16];
            if (CIN % 64 == 0) {
                const float* xr = xin + (size_t)(e0 + srow) * CIN + kbase;
                float4 q0 = *(const float4*)(xr + 0);
                float4 q1 = *(const float4*)(xr + 4);
                float4 q2 = *(const float4*)(xr + 8);
                float4 q3 = *(const float4*)(xr + 12);
                v[0]=q0.x; v[1]=q0.y; v[2]=q0.z; v[3]=q0.w;
                v[4]=q1.x; v[5]=q1.y; v[6]=q1.z; v[7]=q1.w;
                v[8]=q2.x; v[9]=q2.y; v[10]=q2.z; v[11]=q2.w;
                v[12]=q3.x; v[13]=q3.y; v[14]=q3.z; v[15]=q3.w;
            } else {
                const float* xr = xin + (size_t)(e0 + srow) * CIN;
                #pragma unroll
                for (int j = 0; j < 16; ++j)
                    v[j] = (kbase + j < CIN) ? xr[kbase + j] : 0.f;
            }
            #pragma unroll
            for (int g = 0; g < 2; ++g) {
                const int ko = sco + g * 8;
                const int cs = (ko >> 5) & 1;
                const int kb = (ko >> 3) & 3;
                const int blk = kb ^ ((srow >> 1) & 3);
                s16x8 h8, l8;
                #pragma unroll
                for (int j = 0; j < 8; ++j) {
                    unsigned short hb = f2bf(v[g * 8 + j]);
                    h8[j] = (short)hb;
                    l8[j] = (short)f2bf(v[g * 8 + j] - bf2f(hb));
                }
                *(s16x8*)&ash[cs][0][srow][blk * 8] = h8;
                *(s16x8*)&ash[cs][1][srow][blk * 8] = l8;
            }
        }
        {
            float v[16];
            #pragma unroll
            for (int j = 0; j < 16; ++j) {
                const int k = s * 64 + sco + j;
                v[j] = (k < CIN) ? root[(size_t)k * COUT + n0 + srow] : 0.f;
            }
            #pragma unroll
            for (int g = 0; g < 2; ++g) {
                const int ko = sco + g * 8;
                const int cs = (ko >> 5) & 1;
                const int kb = (ko >> 3) & 3;
                const int blk = kb ^ ((srow >> 1) & 3);
                s16x8 h8, l8;
                #pragma unroll
                for (int j = 0; j < 8; ++j) {
                    unsigned short hb = f2bf(v[g * 8 + j]);
                    h8[j] = (short)hb;
                    l8[j] = (short)f2bf(v[g * 8 + j] - bf2f(hb));
                }
                *(s16x8*)&bsh[cs][0][srow][blk * 8] = h8;
                *(s16x8*)&bsh[cs][1][srow][blk * 8] = l8;
            }
        }
        __syncthreads();

        #pragma unroll
        for (int cs = 0; cs < 2; ++cs) {
            const int arow = w * 16 + l15;
            s16x8 Ah = *(const s16x8*)&ash[cs][0][arow][(lg ^ swb) * 8];
            s16x8 Al = *(const s16x8*)&ash[cs][1][arow][(lg ^ swb) * 8];
            #pragma unroll
            for (int nf = 0; nf < 4; ++nf) {
                const int bcol = nf * 16 + l15;
                s16x8 Bh = *(const s16x8*)&bsh[cs][0][bcol][(lg ^ swb) * 8];
                s16x8 Bl = *(const s16x8*)&bsh[cs][1][bcol][(lg ^ swb) * 8];
                ahh[nf] = __builtin_amdgcn_mfma_f32_16x16x32_bf16(Ah, Bh, ahh[nf], 0, 0, 0);
                alh[nf] = __builtin_amdgcn_mfma_f32_16x16x32_bf16(Al, Bh, alh[nf], 0, 0, 0);
                ahl[nf] = __builtin_amdgcn_mfma_f32_16x16x32_bf16(Ah, Bl, ahl[nf], 0, 0, 0);
            }
        }
    }

    __syncthreads();
    #pragma unroll
    for (int nf = 0; nf < 4; ++nf)
        #pragma unroll
        for (int r = 0; r < 4; ++r)
            csh[w * 16 + lg * 4 + r][nf * 16 + l15] = ahh[nf][r] + alh[nf][r] + ahl[nf][r];
    __syncthreads();

    const int tx  = tid & 15;
    const int ty  = tid >> 4;
    const int ty4 = ty * 4;
    const int tx4 = tx * 4;

    float bs[4];
    #pragma unroll
    for (int nq = 0; nq < 4; ++nq) bs[nq] = bias[n0 + tx4 + nq];

    #pragma unroll
    for (int mm = 0; mm < 4; ++mm) {
        const int row = e0 + ty4 + mm;
        float add[4] = {0.f, 0.f, 0.f, 0.f};
        const int b = offs[row], t = offs[row + 1];
        for (int j = b; j < t; ++j) {
            const int e = eid[j];
            #pragma unroll
            for (int z = 0; z < Z; ++z) {
                f16x4 r4 = *(const f16x4*)(part + ((size_t)z * E + e) * COUT + n0 + tx4);
                add[0] += (float)r4.x; add[1] += (float)r4.y;
                add[2] += (float)r4.z; add[3] += (float)r4.w;
            }
        }
        size_t base = (size_t)row * COUT + n0 + tx4;
        #pragma unroll
        for (int nq = 0; nq < 4; ++nq)
            out[base + nq] = elu_f(csh[ty4 + mm][tx4 + nq] + add[nq] + bs[nq]);
    }
}

// ---------------- fused pooling + readout MLP ----------------
__global__ __launch_bounds__(256)
void pool_readout_kernel(const float* __restrict__ hl3, const int* __restrict__ goffs,
                         const float* __restrict__ fc1w, const float* __restrict__ fc1b,
                         const float* __restrict__ fc2w, const float* __restrict__ fc2b,
                         const float* __restrict__ fc3w, const float* __restrict__ fc3b,
                         float* __restrict__ outp)
{
    const int g   = blockIdx.x;
    const int tid = threadIdx.x;
    __shared__ float gm[256];
    __shared__ float a1[128];
    __shared__ float a2[64];
    const int b = goffs[g], t = goffs[g + 1];
    float s = 0.f;
    for (int n = b; n < t; ++n) s += hl3[(size_t)n * 256 + tid];
    gm[tid] = s / fmaxf((float)(t - b), 1.f);
    __syncthreads();
    if (tid < 128) {
        float v = fc1b[tid];
        for (int j = 0; j < 256; ++j) v = fmaf(gm[j], fc1w[j * 128 + tid], v);
        a1[tid] = elu_f(v);
    }
    __syncthreads();
    if (tid < 64) {
        float v = fc2b[tid];
        for (int j = 0; j < 128; ++j) v = fmaf(a1[j], fc2w[j * 64 + tid], v);
        a2[tid] = elu_f(v);
    }
    __syncthreads();
    if (tid == 0) {
        float v = fc3b[0];
        for (int j = 0; j < 64; ++j) v = fmaf(a2[j], fc3w[j], v);
        outp[g] = v;
    }
}

extern "C" void kernel_launch(void* const* d_in, const int* in_sizes, int n_in,
                              void* d_out, int out_size, void* d_ws, size_t ws_size,
                              hipStream_t stream)
{
    const float* x      = (const float*)d_in[0];
    const int*   ei     = (const int*)  d_in[1];
    const float* ea     = (const float*)d_in[2];
    const int*   batch  = (const int*)  d_in[3];
    const float* nn1_w1 = (const float*)d_in[4];
    const float* nn1_b1 = (const float*)d_in[5];
    const float* nn1_w2 = (const float*)d_in[6];
    const float* nn1_b2 = (const float*)d_in[7];
    const float* root1  = (const float*)d_in[8];
    const float* bias1  = (const float*)d_in[9];
    const float* nn2_w1 = (const float*)d_in[10];
    const float* nn2_b1 = (const float*)d_in[11];
    const float* nn2_w2 = (const float*)d_in[12];
    const float* nn2_b2 = (const float*)d_in[13];
    const float* root2  = (const float*)d_in[14];
    const float* bias2  = (const float*)d_in[15];
    const float* nn3_w1 = (const float*)d_in[16];
    const float* nn3_b1 = (const float*)d_in[17];
    const float* nn3_w2 = (const float*)d_in[18];
    const float* nn3_b2 = (const float*)d_in[19];
    const float* root3  = (const float*)d_in[20];
    const float* bias3  = (const float*)d_in[21];
    const float* fc1_w  = (const float*)d_in[22];
    const float* fc1_b  = (const float*)d_in[23];
    const float* fc2_w  = (const float*)d_in[24];
    const float* fc2_b  = (const float*)d_in[25];
    const float* fc3_w  = (const float*)d_in[26];
    const float* fc3_b  = (const float*)d_in[27];

    const int E = in_sizes[2] / 5;    // 4096
    const int N = in_sizes[0] / 37;   // 4096
    const int B = out_size;           // 128
    const int* srcp = ei;
    const int* dstp = ei + E;

    // ---- workspace layout (identical to r8/r12/r14) ----
    const size_t W1H = (size_t)513 * 2 * 128 * 32;   // halfs
    const size_t W2H = (size_t)129 * 4 * 256 * 32;
    const size_t W3H = (size_t)129 * 8 * 256 * 32;
    _Float16* w2h1 = (_Float16*)d_ws;
    _Float16* w2h2 = w2h1 + W1H;
    _Float16* w2h3 = w2h2 + W2H;
    _Float16* h1T  = w2h3 + W3H;                    // [512, E] f16
    _Float16* h2T  = h1T + (size_t)512 * E;         // [128, E]
    _Float16* h3T  = h2T + (size_t)128 * E;         // [128, E]
    _Float16* part = h3T + (size_t)128 * E;         // 32*E*128 == 16*E*256 halfs
    float* fbase = (float*)(part + (size_t)32 * E * 128);
    float* hl1   = fbase;                           // [N,128]
    float* hl2   = hl1 + (size_t)N * 128;           // [N,256]
    float* hl3   = hl2 + (size_t)N * 256;           // [N,256]
    int* ibase   = (int*)(hl3 + (size_t)N * 256);
    int* cnt   = ibase;            // [N]    -- zeroed
    int* cur   = cnt + N;          // [N]    -- zeroed
    int* offs  = cur + N;          // [N+1]
    int* eid   = offs + N + 1;     // [E]
    int* goffs = eid + E;          // [B+1]

    hipMemsetAsync(cnt, 0, 2 * N * sizeof(int), stream);

    // fused prologue: edge MLP (E/64 blocks) + pack1 (1026) + pack2 (516) + pack3 (1032)
    const int nEB = E / 64;
    uber_prologue_kernel<<<nEB + 1026 + 516 + 1032, 256, 0, stream>>>(
        ea, dstp, cnt,
        nn1_w1, nn1_b1, h1T, nn2_w1, nn2_b1, h2T, nn3_w1, nn3_b1, h3T, E,
        nn1_w2, nn1_b2, w2h1, nn2_w2, nn2_b2, w2h2, nn3_w2, nn3_b2, w2h3);

    csr_scan_graph_kernel<<<1, 256, 0, stream>>>(cnt, offs, N, batch, goffs, B, N);
    csr_fill_kernel<<<(E + 255) / 256, 256, 0, stream>>>(dstp, offs, cur, eid, E);

    // layer 1: KH=512, CIN=37, COUT=128; CSPLIT=2 (KF=1), NY=2; khg=33 -> Z=32
    msg_mfma_kernel<512, 37, 128, 2, 2, 2, 33><<<512, 256, 0, stream>>>(
        x, h1T, w2h1, srcp, part, E, 33);
    node_mfma_kernel<37, 128, 32><<<dim3(N / 64, 2), 256, 0, stream>>>(
        x, root1, part, offs, eid, bias1, hl1, E);

    // layer 2: KH=128, CIN=128, COUT=256; CSPLIT=4 (KF=1), NY=4; khg=33 -> Z=16
    msg_mfma_kernel<128, 128, 256, 4, 4, 4, 33><<<512, 256, 0, stream>>>(
        hl1, h2T, w2h2, srcp, part, E, 33);
    node_mfma_kernel<128, 256, 16><<<dim3(N / 64, 4), 256, 0, stream>>>(
        hl1, root2, part, offs, eid, bias2, hl2, E);

    // layer 3: KH=128, CIN=256, COUT=256; CSPLIT=8 (KF=1), NY=4; khg=65 -> Z=16
    msg_mfma_kernel<128, 256, 256, 8, 8, 4, 65><<<512, 256, 0, stream>>>(
        hl2, h3T, w2h3, srcp, part, E, 65);
    node_mfma_kernel<256, 256, 16><<<dim3(N / 64, 4), 256, 0, stream>>>(
        hl2, root3, part, offs, eid, bias3, hl3, E);

    pool_readout_kernel<<<B, 256, 0, stream>>>(hl3, goffs, fc1_w, fc1_b,
                                               fc2_w, fc2_b, fc3_w, fc3_b,
                                               (float*)d_out);
}

// Round 16
// 280.085 us; speedup vs baseline: 1.0770x; 1.0770x over previous
//
#include <hip/hip_runtime.h>
#include <cstdint>
#include <cstddef>

typedef float f32x4 __attribute__((ext_vector_type(4)));
typedef _Float16 f16x8 __attribute__((ext_vector_type(8)));
typedef _Float16 f16x4 __attribute__((ext_vector_type(4)));
typedef short s16x8 __attribute__((ext_vector_type(8)));

__device__ __forceinline__ float elu_f(float x) { return x > 0.f ? x : expm1f(x); }

__device__ __forceinline__ unsigned short f2bf(float f) {
    unsigned u = __float_as_uint(f);
    return (unsigned short)((u + 0x7FFFu + ((u >> 16) & 1u)) >> 16);
}
__device__ __forceinline__ float bf2f(unsigned short b) {
    return __uint_as_float(((unsigned)b) << 16);
}

__device__ __forceinline__ void gload_lds16(const void* g, void* l)
{
    __builtin_amdgcn_global_load_lds(
        (const __attribute__((address_space(1))) void*)g,
        (__attribute__((address_space(3))) void*)l,
        16, 0, 0);
}

// ================= fused prologue: edge-MLP (+dst count) and the 3 w2 packs =========
// pack layout (proven r5/r6/r8): fp16 chunks [kh*KFTOT+c][COUT][32] with 16B-block swizzle
// blk = (kk>>3) ^ ((n>>1)&3) so linear global_load_lds + swizzled ds_read is conflict-free.
template <int CIN, int COUT, int KFTOT>
__device__ __forceinline__
void pack_body(int bid, int tid, const float* __restrict__ w2, const float* __restrict__ b2,
               _Float16* __restrict__ w2h, int KH, float* tile /* [32][COUT+2] */)
{
    const int kh = bid / KFTOT;
    const int c  = bid - kh * KFTOT;
    const int CP = 32 * COUT;
    for (int i = tid; i < CP; i += 256) {
        int kk = i / COUT, n = i - kk * COUT;
        int kg = c * 32 + kk;
        float v = 0.f;
        if (kg < CIN) v = (kh < KH) ? w2[((size_t)kh * CIN + kg) * COUT + n]
                                    : b2[(size_t)kg * COUT + n];
        tile[kk * (COUT + 2) + n] = v;
    }
    __syncthreads();
    _Float16* outp = w2h + (size_t)bid * CP;
    for (int i = tid; i < CP; i += 256) {
        int n = i >> 5, kk = i & 31;
        int blk = (kk >> 3) ^ ((n >> 1) & 3);
        outp[n * 32 + blk * 8 + (kk & 7)] = (_Float16)tile[kk * (COUT + 2) + n];
    }
}

__global__ __launch_bounds__(256)
void uber_prologue_kernel(const float* __restrict__ ea,
                          const int* __restrict__ dst, int* __restrict__ cnt,
                          const float* __restrict__ w1a, const float* __restrict__ b1a, _Float16* __restrict__ h1T,
                          const float* __restrict__ w1b, const float* __restrict__ b1b, _Float16* __restrict__ h2T,
                          const float* __restrict__ w1c, const float* __restrict__ b1c, _Float16* __restrict__ h3T,
                          int E,
                          const float* __restrict__ w2a, const float* __restrict__ b2a, _Float16* __restrict__ w2h1,
                          const float* __restrict__ w2b, const float* __restrict__ b2b, _Float16* __restrict__ w2h2,
                          const float* __restrict__ w2c, const float* __restrict__ b2c, _Float16* __restrict__ w2h3)
{
    __shared__ __align__(16) float smem[32 * 258];
    const int tid = threadIdx.x;
    const int nEB = E >> 6;
    int b = blockIdx.x;

    if (b < nEB) {
        // ---- edge MLP ----
        const int e0 = b * 64;
        const int el = tid & 63;
        const int cg = tid >> 6;
        if (tid < 64) atomicAdd(&cnt[dst[e0 + tid]], 1);
        float* a = smem;                       // [64][5]
        for (int i = tid; i < 320; i += 256) a[(i / 5) * 5 + (i % 5)] = ea[e0 * 5 + i];
        __syncthreads();
        float av[5];
        #pragma unroll
        for (int j = 0; j < 5; ++j) av[j] = a[el * 5 + j];
        #pragma unroll 4
        for (int t = 0; t < 128; ++t) {
            const int ch = t * 4 + cg;
            float s = b1a[ch];
            #pragma unroll
            for (int j = 0; j < 5; ++j) s = fmaf(av[j], w1a[j * 512 + ch], s);
            h1T[(size_t)ch * E + e0 + el] = (_Float16)fmaxf(s, 0.f);
        }
        #pragma unroll 4
        for (int t = 0; t < 32; ++t) {
            const int ch = t * 4 + cg;
            float s = b1b[ch];
            float u = b1c[ch];
            #pragma unroll
            for (int j = 0; j < 5; ++j) {
                s = fmaf(av[j], w1b[j * 128 + ch], s);
                u = fmaf(av[j], w1c[j * 128 + ch], u);
            }
            h2T[(size_t)ch * E + e0 + el] = (_Float16)fmaxf(s, 0.f);
            h3T[(size_t)ch * E + e0 + el] = (_Float16)fmaxf(u, 0.f);
        }
        return;
    }
    b -= nEB;
    if (b < 513 * 2) { pack_body<37, 128, 2>(b, tid, w2a, b2a, w2h1, 512, smem); return; }
    b -= 513 * 2;
    if (b < 129 * 4) { pack_body<128, 256, 4>(b, tid, w2b, b2b, w2h2, 128, smem); return; }
    b -= 129 * 4;
    pack_body<256, 256, 8>(b, tid, w2c, b2c, w2h3, 128, smem);
}

// ---------------- CSR scan (+ fused graph offsets) ----------------
__global__ __launch_bounds__(256)
void csr_scan_graph_kernel(const int* __restrict__ cnt, int* __restrict__ offs, int N,
                           const int* __restrict__ batch, int* __restrict__ goffs, int B,
                           int NN)
{
    __shared__ int sums[256];
    __shared__ int pref[257];
    const int tid = threadIdx.x;
    const int per = N / 256;
    int loc = 0;
    for (int i = 0; i < per; ++i) loc += cnt[tid * per + i];
    sums[tid] = loc;
    __syncthreads();
    if (tid == 0) {
        int s = 0; pref[0] = 0;
        for (int i = 0; i < 256; ++i) { s += sums[i]; pref[i + 1] = s; }
    }
    __syncthreads();
    int run = pref[tid];
    for (int i = 0; i < per; ++i) { offs[tid * per + i] = run; run += cnt[tid * per + i]; }
    if (tid == 255) offs[N] = run;
    for (int g = tid; g <= B; g += 256) {
        int lo = 0, hi = NN;
        while (lo < hi) { int mid = (lo + hi) >> 1; if (batch[mid] < g) lo = mid + 1; else hi = mid; }
        goffs[g] = lo;
    }
}

__global__ __launch_bounds__(256)
void csr_fill_kernel(const int* __restrict__ dst, const int* __restrict__ offs,
                     int* __restrict__ cur, int* __restrict__ eid, int E)
{
    int e = blockIdx.x * 256 + threadIdx.x;
    if (e < E) {
        int d = dst[e];
        int p = offs[d] + atomicAdd(&cur[d], 1);
        eid[p] = e;
    }
}

// ---------------- MFMA message kernel (r12, proven 67.5us): 16x16x32, mf=8, KF=1 ------
template <int KH, int CIN, int COUT, int KFTOT, int CSPLIT, int NY>
__global__ __launch_bounds__(256, 2)
void msg_mfma_kernel(const float* __restrict__ xin,      // [*, CIN] fp32 (gathered via src)
                     const _Float16* __restrict__ hT,    // [KH, E] f16
                     const _Float16* __restrict__ w2h,   // packed+swizzled
                     const int* __restrict__ src,
                     _Float16* __restrict__ part,        // [NZ][E][COUT]
                     int E, int khg_per)
{
    constexpr int BM = 512;
    constexpr int KF = KFTOT / CSPLIT;
    static_assert(KF == 1, "mf=8 msg kernel expects one 32-k chunk per block");

    __shared__ __align__(16) _Float16 bsh[2][64][32];
    __shared__ int s_src[BM];

    const int tid  = threadIdx.x;
    const int lane = tid & 63;
    const int w    = tid >> 6;        // wave -> rows w*128 .. w*128+127
    const int l15  = lane & 15;
    const int lg   = lane >> 4;       // 0..3  (k-quarter)
    const int swb  = (l15 >> 1) & 3;  // read-side swizzle

    const int nwg = gridDim.x;
    const int bid = blockIdx.x;
    const int swz = (bid & 7) * (nwg >> 3) + (bid >> 3);
    const int m    = swz & 7;          // 8 m-blocks of 512 edges
    const int rest = swz >> 3;
    const int y    = rest % NY;
    const int zz   = rest / NY;
    const int cinH = zz % CSPLIT;
    const int zkh  = zz / CSPLIT;

    const int e0  = m * BM;
    const int n0  = y * 64;
    const int k0  = cinH * 32;
    const int kh0 = zkh * khg_per;
    const int kh1 = min(kh0 + khg_per, KH + 1);

    s_src[tid]       = src[e0 + tid];
    s_src[tid + 256] = src[e0 + tid + 256];
    __syncthreads();

    f16x8 a_[8];
    #pragma unroll
    for (int mf = 0; mf < 8; ++mf) {
        const int eloc = w * 128 + mf * 16 + l15;
        const float* xrow = xin + (size_t)s_src[eloc] * CIN + k0;
        if (CIN % 32 == 0) {
            float4 p0 = *(const float4*)(xrow + lg * 8);
            float4 p1 = *(const float4*)(xrow + lg * 8 + 4);
            a_[mf][0] = (_Float16)p0.x; a_[mf][1] = (_Float16)p0.y;
            a_[mf][2] = (_Float16)p0.z; a_[mf][3] = (_Float16)p0.w;
            a_[mf][4] = (_Float16)p1.x; a_[mf][5] = (_Float16)p1.y;
            a_[mf][6] = (_Float16)p1.z; a_[mf][7] = (_Float16)p1.w;
        } else {
            #pragma unroll
            for (int j = 0; j < 8; ++j) {
                int kk = lg * 8 + j;
                float v = (k0 + kk < CIN) ? xrow[kk] : 0.f;
                a_[mf][j] = (_Float16)v;
            }
        }
    }

    f32x4 msg[8][4];
    #pragma unroll
    for (int mf = 0; mf < 8; ++mf)
        #pragma unroll
        for (int nf = 0; nf < 4; ++nf) msg[mf][nf] = 0.f;

    auto stage = [&](int khg, int pp) {
        if (khg >= kh1) return;
        const size_t chunk = (size_t)khg * KFTOT + cinH;
        const char* g = (const char*)(w2h + (chunk * COUT + n0) * 32) + (size_t)tid * 16;
        char* l = (char*)(&bsh[pp][0][0]) + (tid >> 6) * 1024;
        gload_lds16(g, l);
    };

    stage(kh0, 0);

    int p = 0;
    for (int khg = kh0; khg < kh1; ++khg) {
        __syncthreads();                    // slab p ready (vmcnt drained); p^1 free

        stage(khg + 1, p ^ 1);              // DMA in flight across compute + next barrier

        _Float16 hh[8];
        if (khg < KH) {
            const _Float16* hp = hT + (size_t)khg * E + e0 + w * 128 + l15;
            #pragma unroll
            for (int mf = 0; mf < 8; ++mf) hh[mf] = hp[mf * 16];
        } else {
            #pragma unroll
            for (int mf = 0; mf < 8; ++mf) hh[mf] = (_Float16)1.0f;
        }

        f16x8 Bv[4];
        #pragma unroll
        for (int nf = 0; nf < 4; ++nf)
            Bv[nf] = *(const f16x8*)&bsh[p][nf * 16 + l15][(lg ^ swb) * 8];

        #pragma unroll
        for (int mf = 0; mf < 8; ++mf) {
            f16x8 ah = a_[mf] * hh[mf];
            #pragma unroll
            for (int nf = 0; nf < 4; ++nf)
                msg[mf][nf] = __builtin_amdgcn_mfma_f32_16x16x32_f16(ah, Bv[nf], msg[mf][nf], 0, 0, 0);
        }
        p ^= 1;
    }

    _Float16* pb = part + ((size_t)zz * E + e0) * COUT + n0;
    #pragma unroll
    for (int mf = 0; mf < 8; ++mf)
        #pragma unroll
        for (int r = 0; r < 4; ++r) {
            const int row = w * 128 + mf * 16 + lg * 4 + r;
            #pragma unroll
            for (int nf = 0; nf < 4; ++nf)
                pb[(size_t)row * COUT + nf * 16 + l15] = (_Float16)msg[mf][nf][r];
        }
}

// ---------------- node GEMM via bf16 hi/lo MFMA + fused CSR gather (r14-proven) -------
// out[n] = elu( x[n]@root + sum_{e: dst=n} sum_z part[z][e] + bias )
template <int CIN, int COUT, int Z>
__global__ __launch_bounds__(256, 2)
void node_mfma_kernel(const float* __restrict__ xin,
                      const float* __restrict__ root,
                      const _Float16* __restrict__ part,
                      const int* __restrict__ offs,
                      const int* __restrict__ eid,
                      const float* __restrict__ bias,
                      float* __restrict__ out, int E)
{
    constexpr int KC    = (CIN + 31) / 32;
    constexpr int NSTEP = KC / 2;

    __shared__ __align__(16) char smem[32768];
    short (*ash)[2][64][32] = (short (*)[2][64][32])smem;
    short (*bsh)[2][64][32] = (short (*)[2][64][32])(smem + 16384);
    float (*csh)[68]        = (float (*)[68])smem;

    const int tid  = threadIdx.x;
    const int lane = tid & 63;
    const int w    = tid >> 6;
    const int l15  = lane & 15;
    const int lg   = lane >> 4;
    const int swb  = (l15 >> 1) & 3;
    const int e0   = blockIdx.x * 64;
    const int n0   = blockIdx.y * 64;

    f32x4 ahh[4], alh[4], ahl[4];
    #pragma unroll
    for (int nf = 0; nf < 4; ++nf) { ahh[nf] = 0.f; alh[nf] = 0.f; ahl[nf] = 0.f; }

    const int srow = tid & 63;
    const int sco  = (tid >> 6) * 16;

    for (int s = 0; s < NSTEP; ++s) {
        __syncthreads();

        {
            const int kbase = s * 64 + sco;
            float v[16];
            if (CIN % 64 == 0) {
                const float* xr = xin + (size_t)(e0 + srow) * CIN + kbase;
                float4 q0 = *(const float4*)(xr + 0);
                float4 q1 = *(const float4*)(xr + 4);
                float4 q2 = *(const float4*)(xr + 8);
                float4 q3 = *(const float4*)(xr + 12);
                v[0]=q0.x; v[1]=q0.y; v[2]=q0.z; v[3]=q0.w;
                v[4]=q1.x; v[5]=q1.y; v[6]=q1.z; v[7]=q1.w;
                v[8]=q2.x; v[9]=q2.y; v[10]=q2.z; v[11]=q2.w;
                v[12]=q3.x; v[13]=q3.y; v[14]=q3.z; v[15]=q3.w;
            } else {
                const float* xr = xin + (size_t)(e0 + srow) * CIN;
                #pragma unroll
                for (int j = 0; j < 16; ++j)
                    v[j] = (kbase + j < CIN) ? xr[kbase + j] : 0.f;
            }
            #pragma unroll
            for (int g = 0; g < 2; ++g) {
                const int ko = sco + g * 8;
                const int cs = (ko >> 5) & 1;
                const int kb = (ko >> 3) & 3;
                const int blk = kb ^ ((srow >> 1) & 3);
                s16x8 h8, l8;
                #pragma unroll
                for (int j = 0; j < 8; ++j) {
                    unsigned short hb = f2bf(v[g * 8 + j]);
                    h8[j] = (short)hb;
                    l8[j] = (short)f2bf(v[g * 8 + j] - bf2f(hb));
                }
                *(s16x8*)&ash[cs][0][srow][blk * 8] = h8;
                *(s16x8*)&ash[cs][1][srow][blk * 8] = l8;
            }
        }
        {
            float v[16];
            #pragma unroll
            for (int j = 0; j < 16; ++j) {
                const int k = s * 64 + sco + j;
                v[j] = (k < CIN) ? root[(size_t)k * COUT + n0 + srow] : 0.f;
            }
            #pragma unroll
            for (int g = 0; g < 2; ++g) {
                const int ko = sco + g * 8;
                const int cs = (ko >> 5) & 1;
                const int kb = (ko >> 3) & 3;
                const int blk = kb ^ ((srow >> 1) & 3);
                s16x8 h8, l8;
                #pragma unroll
                for (int j = 0; j < 8; ++j) {
                    unsigned short hb = f2bf(v[g * 8 + j]);
                    h8[j] = (short)hb;
                    l8[j] = (short)f2bf(v[g * 8 + j] - bf2f(hb));
                }
                *(s16x8*)&bsh[cs][0][srow][blk * 8] = h8;
                *(s16x8*)&bsh[cs][1][srow][blk * 8] = l8;
            }
        }
        __syncthreads();

        #pragma unroll
        for (int cs = 0; cs < 2; ++cs) {
            const int arow = w * 16 + l15;
            s16x8 Ah = *(const s16x8*)&ash[cs][0][arow][(lg ^ swb) * 8];
            s16x8 Al = *(const s16x8*)&ash[cs][1][arow][(lg ^ swb) * 8];
            #pragma unroll
            for (int nf = 0; nf < 4; ++nf) {
                const int bcol = nf * 16 + l15;
                s16x8 Bh = *(const s16x8*)&bsh[cs][0][bcol][(lg ^ swb) * 8];
                s16x8 Bl = *(const s16x8*)&bsh[cs][1][bcol][(lg ^ swb) * 8];
                ahh[nf] = __builtin_amdgcn_mfma_f32_16x16x32_bf16(Ah, Bh, ahh[nf], 0, 0, 0);
                alh[nf] = __builtin_amdgcn_mfma_f32_16x16x32_bf16(Al, Bh, alh[nf], 0, 0, 0);
                ahl[nf] = __builtin_amdgcn_mfma_f32_16x16x32_bf16(Ah, Bl, ahl[nf], 0, 0, 0);
            }
        }
    }

    __syncthreads();
    #pragma unroll
    for (int nf = 0; nf < 4; ++nf)
        #pragma unroll
        for (int r = 0; r < 4; ++r)
            csh[w * 16 + lg * 4 + r][nf * 16 + l15] = ahh[nf][r] + alh[nf][r] + ahl[nf][r];
    __syncthreads();

    const int tx  = tid & 15;
    const int ty  = tid >> 4;
    const int ty4 = ty * 4;
    const int tx4 = tx * 4;

    float bs[4];
    #pragma unroll
    for (int nq = 0; nq < 4; ++nq) bs[nq] = bias[n0 + tx4 + nq];

    #pragma unroll
    for (int mm = 0; mm < 4; ++mm) {
        const int row = e0 + ty4 + mm;
        float add[4] = {0.f, 0.f, 0.f, 0.f};
        const int b = offs[row], t = offs[row + 1];
        for (int j = b; j < t; ++j) {
            const int e = eid[j];
            #pragma unroll
            for (int z = 0; z < Z; ++z) {
                f16x4 r4 = *(const f16x4*)(part + ((size_t)z * E + e) * COUT + n0 + tx4);
                add[0] += (float)r4.x; add[1] += (float)r4.y;
                add[2] += (float)r4.z; add[3] += (float)r4.w;
            }
        }
        size_t base = (size_t)row * COUT + n0 + tx4;
        #pragma unroll
        for (int nq = 0; nq < 4; ++nq)
            out[base + nq] = elu_f(csh[ty4 + mm][tx4 + nq] + add[nq] + bs[nq]);
    }
}

// ---------------- fused pooling + readout MLP ----------------
__global__ __launch_bounds__(256)
void pool_readout_kernel(const float* __restrict__ hl3, const int* __restrict__ goffs,
                         const float* __restrict__ fc1w, const float* __restrict__ fc1b,
                         const float* __restrict__ fc2w, const float* __restrict__ fc2b,
                         const float* __restrict__ fc3w, const float* __restrict__ fc3b,
                         float* __restrict__ outp)
{
    const int g   = blockIdx.x;
    const int tid = threadIdx.x;
    __shared__ float gm[256];
    __shared__ float a1[128];
    __shared__ float a2[64];
    const int b = goffs[g], t = goffs[g + 1];
    float s = 0.f;
    for (int n = b; n < t; ++n) s += hl3[(size_t)n * 256 + tid];
    gm[tid] = s / fmaxf((float)(t - b), 1.f);
    __syncthreads();
    if (tid < 128) {
        float v = fc1b[tid];
        for (int j = 0; j < 256; ++j) v = fmaf(gm[j], fc1w[j * 128 + tid], v);
        a1[tid] = elu_f(v);
    }
    __syncthreads();
    if (tid < 64) {
        float v = fc2b[tid];
        for (int j = 0; j < 128; ++j) v = fmaf(a1[j], fc2w[j * 64 + tid], v);
        a2[tid] = elu_f(v);
    }
    __syncthreads();
    if (tid == 0) {
        float v = fc3b[0];
        for (int j = 0; j < 64; ++j) v = fmaf(a2[j], fc3w[j], v);
        outp[g] = v;
    }
}

extern "C" void kernel_launch(void* const* d_in, const int* in_sizes, int n_in,
                              void* d_out, int out_size, void* d_ws, size_t ws_size,
                              hipStream_t stream)
{
    const float* x      = (const float*)d_in[0];
    const int*   ei     = (const int*)  d_in[1];
    const float* ea     = (const float*)d_in[2];
    const int*   batch  = (const int*)  d_in[3];
    const float* nn1_w1 = (const float*)d_in[4];
    const float* nn1_b1 = (const float*)d_in[5];
    const float* nn1_w2 = (const float*)d_in[6];
    const float* nn1_b2 = (const float*)d_in[7];
    const float* root1  = (const float*)d_in[8];
    const float* bias1  = (const float*)d_in[9];
    const float* nn2_w1 = (const float*)d_in[10];
    const float* nn2_b1 = (const float*)d_in[11];
    const float* nn2_w2 = (const float*)d_in[12];
    const float* nn2_b2 = (const float*)d_in[13];
    const float* root2  = (const float*)d_in[14];
    const float* bias2  = (const float*)d_in[15];
    const float* nn3_w1 = (const float*)d_in[16];
    const float* nn3_b1 = (const float*)d_in[17];
    const float* nn3_w2 = (const float*)d_in[18];
    const float* nn3_b2 = (const float*)d_in[19];
    const float* root3  = (const float*)d_in[20];
    const float* bias3  = (const float*)d_in[21];
    const float* fc1_w  = (const float*)d_in[22];
    const float* fc1_b  = (const float*)d_in[23];
    const float* fc2_w  = (const float*)d_in[24];
    const float* fc2_b  = (const float*)d_in[25];
    const float* fc3_w  = (const float*)d_in[26];
    const float* fc3_b  = (const float*)d_in[27];

    const int E = in_sizes[2] / 5;    // 4096
    const int N = in_sizes[0] / 37;   // 4096
    const int B = out_size;           // 128
    const int* srcp = ei;
    const int* dstp = ei + E;

    // ---- workspace layout (identical to r8/r12/r14) ----
    const size_t W1H = (size_t)513 * 2 * 128 * 32;   // halfs
    const size_t W2H = (size_t)129 * 4 * 256 * 32;
    const size_t W3H = (size_t)129 * 8 * 256 * 32;
    _Float16* w2h1 = (_Float16*)d_ws;
    _Float16* w2h2 = w2h1 + W1H;
    _Float16* w2h3 = w2h2 + W2H;
    _Float16* h1T  = w2h3 + W3H;                    // [512, E] f16
    _Float16* h2T  = h1T + (size_t)512 * E;         // [128, E]
    _Float16* h3T  = h2T + (size_t)128 * E;         // [128, E]
    _Float16* part = h3T + (size_t)128 * E;         // 32*E*128 == 16*E*256 halfs
    float* fbase = (float*)(part + (size_t)32 * E * 128);
    float* hl1   = fbase;                           // [N,128]
    float* hl2   = hl1 + (size_t)N * 128;           // [N,256]
    float* hl3   = hl2 + (size_t)N * 256;           // [N,256]
    int* ibase   = (int*)(hl3 + (size_t)N * 256);
    int* cnt   = ibase;            // [N]    -- zeroed
    int* cur   = cnt + N;          // [N]    -- zeroed
    int* offs  = cur + N;          // [N+1]
    int* eid   = offs + N + 1;     // [E]
    int* goffs = eid + E;          // [B+1]

    hipMemsetAsync(cnt, 0, 2 * N * sizeof(int), stream);

    // fused prologue: edge MLP (E/64 blocks) + pack1 (1026) + pack2 (516) + pack3 (1032)
    const int nEB = E / 64;
    uber_prologue_kernel<<<nEB + 1026 + 516 + 1032, 256, 0, stream>>>(
        ea, dstp, cnt,
        nn1_w1, nn1_b1, h1T, nn2_w1, nn2_b1, h2T, nn3_w1, nn3_b1, h3T, E,
        nn1_w2, nn1_b2, w2h1, nn2_w2, nn2_b2, w2h2, nn3_w2, nn3_b2, w2h3);

    csr_scan_graph_kernel<<<1, 256, 0, stream>>>(cnt, offs, N, batch, goffs, B, N);
    csr_fill_kernel<<<(E + 255) / 256, 256, 0, stream>>>(dstp, offs, cur, eid, E);

    // layer 1: KH=512, CIN=37, COUT=128; KFTOT=2, CSPLIT=2 (KF=1), NY=2; khg=33 -> Z=32
    msg_mfma_kernel<512, 37, 128, 2, 2, 2><<<512, 256, 0, stream>>>(
        x, h1T, w2h1, srcp, part, E, 33);
    node_mfma_kernel<37, 128, 32><<<dim3(N / 64, 2), 256, 0, stream>>>(
        x, root1, part, offs, eid, bias1, hl1, E);

    // layer 2: KH=128, CIN=128, COUT=256; KFTOT=4, CSPLIT=4 (KF=1), NY=4; khg=33 -> Z=16
    msg_mfma_kernel<128, 128, 256, 4, 4, 4><<<512, 256, 0, stream>>>(
        hl1, h2T, w2h2, srcp, part, E, 33);
    node_mfma_kernel<128, 256, 16><<<dim3(N / 64, 4), 256, 0, stream>>>(
        hl1, root2, part, offs, eid, bias2, hl2, E);

    // layer 3: KH=128, CIN=256, COUT=256; KFTOT=8, CSPLIT=8 (KF=1), NY=4; khg=65 -> Z=16
    msg_mfma_kernel<128, 256, 256, 8, 8, 4><<<512, 256, 0, stream>>>(
        hl2, h3T, w2h3, srcp, part, E, 65);
    node_mfma_kernel<256, 256, 16><<<dim3(N / 64, 4), 256, 0, stream>>>(
        hl2, root3, part, offs, eid, bias3, hl3, E);

    pool_readout_kernel<<<B, 256, 0, stream>>>(hl3, goffs, fc1_w, fc1_b,
                                               fc2_w, fc2_b, fc3_w, fc3_b,
                                               (float*)d_out);
}